// Round 7
// baseline (171.572 us; speedup 1.0000x reference)
//
#include <hip/hip_runtime.h>

// ContrastiveLoss: loss = sum_n [ log(sum_j exp(2*<ne_n,ne_j>)) - 2*<ne_n,nt_n> ] / (2N)
// N=8192, D=512.
// R18b = R18 resubmitted verbatim (round 6 failed at the container level --
// "MI355X container failed twice" -- with no kernel verdict; audit found no
// divergent barriers, no buffer race, no resource violation).
// R18: LDS dedup WITHOUT global_load_lds. R13/R17 (identical counters, two
// different register structures) prove the global_load_lds path itself
// generates ~120 MB HBM fetch + ~208 MB write-back when staging a 4 MB
// L2-resident buffer (streaming/no-allocate behavior through poisoned
// caches); normal vector loads (R16) show near-logical traffic. R16 also
// shows direct-to-VGPR saturates at ~9-13 TB/s realized L2 on 532 MB of
// duplicated demand -> ~40-59 us regardless of compute rate. Fix: T14
// reg-staged LDS: global->VGPR (L2-cached) -> ds_write_b128 -> ds_read.
//   - L2 demand halves (266 MB): each block reads its 128 KB operand set once.
//   - Loads for window w+1 issue BEFORE MFMA(w); ds_write after (vmcnt wait
//     rides under ~550 cyc of MFMA) -> L2 latency hidden.
//   - One barrier per window: write buf^1 only after the barrier that ended
//     its reads; barrier then publishes it for the next window.
//   - Staging/read addressing byte-identical to R17's verified map.
//   - Regs: 64 AGPR acc + 16 stage + 16 frag + ~16 addr ~= 115, no spill at
//     __launch_bounds__(256,3) (cap 168) -> 3 blocks/CU, 12 waves/CU.
//   k_norm : unchanged (R13/R14/R17-verified MX 16B-half-interleaved layout).
//   k_gemm : 2x2 waves x 2x2 mfma_scale_f32_32x32x64_f8f6f4, unit E8M0
//            scales; 32x32 C/D epilogue (col=lane&31,
//            row=(r&3)+8*(r>>2)+4*(lane>>5)); symmetric triangle; XCD sched.
//   k_final: unchanged.

typedef __attribute__((ext_vector_type(16))) float floatx16;
typedef __attribute__((ext_vector_type(4)))  int   intx4;
typedef __attribute__((ext_vector_type(8)))  int   intx8;
typedef unsigned int u32;

#define N 8192
#define D 512
#define NT 64            // 128-row tiles per dim

// Per-XCD segment tables: 5 segments each = [diag36, off64, off64, off64, half32].
__device__ __constant__ unsigned char seg_ga[8][5] = {
    {0,0,0,0,0},{1,1,1,1,0},{2,2,2,2,2},{3,3,3,3,2},
    {4,0,0,0,4},{5,1,1,1,4},{6,2,3,4,6},{7,4,5,5,6}};
__device__ __constant__ unsigned char seg_gb[8][5] = {
    {0,2,3,4,1},{1,2,3,4,1},{2,5,6,7,3},{3,5,6,7,3},
    {4,5,6,7,5},{5,5,6,7,5},{6,4,4,6,7},{7,7,6,7,7}};

__global__ __launch_bounds__(256) void k_norm(const float* __restrict__ emb,
                                              const float* __restrict__ tgt,
                                              unsigned char* __restrict__ neb,
                                              float* __restrict__ pos,
                                              float* __restrict__ out) {
    if (blockIdx.x == 0 && threadIdx.x == 0) *out = 0.0f;   // replaces memset dispatch
    int wave = threadIdx.x >> 6;
    int lane = threadIdx.x & 63;
    int row  = blockIdx.x * 4 + wave;          // one wave per row; lane holds k=lane*8..+8
    const float4* e4 = (const float4*)(emb + (size_t)row * D) + lane * 2;
    const float4* t4 = (const float4*)(tgt + (size_t)row * D) + lane * 2;
    float4 e0 = e4[0], e1 = e4[1];
    float4 t0 = t4[0], t1 = t4[1];
    float ee = e0.x*e0.x + e0.y*e0.y + e0.z*e0.z + e0.w*e0.w
             + e1.x*e1.x + e1.y*e1.y + e1.z*e1.z + e1.w*e1.w;
    float tt = t0.x*t0.x + t0.y*t0.y + t0.z*t0.z + t0.w*t0.w
             + t1.x*t1.x + t1.y*t1.y + t1.z*t1.z + t1.w*t1.w;
    float et = e0.x*t0.x + e0.y*t0.y + e0.z*t0.z + e0.w*t0.w
             + e1.x*t1.x + e1.y*t1.y + e1.z*t1.z + e1.w*t1.w;
    #pragma unroll
    for (int off = 1; off < 64; off <<= 1) {
        ee += __shfl_xor(ee, off);
        tt += __shfl_xor(tt, off);
        et += __shfl_xor(et, off);
    }
    float se = fmaxf(sqrtf(ee), 1e-12f);
    float st = fmaxf(sqrtf(tt), 1e-12f);
    if (lane == 0) pos[row] = et / (se * st);
    float inv = 1.0f / se;
    // pack 8 e4m3 bytes (k ascending) via HW RNE converts
    int w0 = __builtin_amdgcn_cvt_pk_fp8_f32(e0.x * inv, e0.y * inv, 0, false);
    w0     = __builtin_amdgcn_cvt_pk_fp8_f32(e0.z * inv, e0.w * inv, w0, true);
    int w1 = __builtin_amdgcn_cvt_pk_fp8_f32(e1.x * inv, e1.y * inv, 0, false);
    w1     = __builtin_amdgcn_cvt_pk_fp8_f32(e1.z * inv, e1.w * inv, w1, true);
    uint2 pk; pk.x = (unsigned)w0; pk.y = (unsigned)w1;
    // MX layout (verified R13/R14/R17). Row r, byte kb = lane*8:
    //   block b32 = r>>5 (16 KB), window w = kb>>6 (2 KB), khalf g = (kb>>5)&1,
    //   16B-half h = (kb>>4)&1, uint2 parity = lane&1.
    //   byte addr = b32*16384 + w*2048 + h*1024 + (g*32 + (r&31))*16 + (lane&1)*8
    size_t u2idx = (size_t)(row >> 5) * 2048
                 + (size_t)(lane >> 3) * 256
                 + (size_t)((lane >> 1) & 1) * 128
                 + (size_t)(((lane >> 2) & 1) * 32 + (row & 31)) * 2
                 + (lane & 1);
    ((uint2*)neb)[u2idx] = pk;
}

__global__ __launch_bounds__(256, 3) void k_gemm(const unsigned char* __restrict__ neb,
                                                 float* __restrict__ partial) {
    // XCD-partitioned decode: x = XCD stream, s = sequence within stream
    const int x = (int)(blockIdx.x & 7);
    int s = (int)(blockIdx.x >> 3);          // 0..259
    int seg, u;
    if (s < 36)       { seg = 0; u = s; }
    else if (s < 100) { seg = 1; u = s - 36; }
    else if (s < 164) { seg = 2; u = s - 100; }
    else if (s < 228) { seg = 3; u = s - 164; }
    else              { seg = 4; u = s - 228 + ((x & 1) ? 32 : 0); }
    const int ga = seg_ga[x][seg], gb = seg_gb[x][seg];
    int bi, bj;
    if (seg == 0) {                           // diag supertile: tri decode in 8x8
        int di = 0;
        while (u >= 8 - di) { u -= 8 - di; ++di; }
        bi = ga * 8 + di; bj = gb * 8 + di + u;
    } else {
        bi = ga * 8 + (u >> 3); bj = gb * 8 + (u & 7);
    }

    __shared__ unsigned char smem[2][16384];   // double-buffered 64-k window: A 8K | B 8K

    const int tid  = threadIdx.x;
    const int i0   = bi * 128, j0 = bj * 128;
    const int wave = tid >> 6, lane = tid & 63;
    const int wrow = wave >> 1, wcol = wave & 1;   // 2x2 waves, each 64x64

    // --- staging plan (byte-identical addressing to R17, ds_write instead of
    // DMA): wave v, lane l handles 4 x 16 B per window:
    //   src: A blocks (i0/32 + (v>>1)) and +2; B blocks (j0/32 + (v>>1)) and +2,
    //        each at (v&1)*1024 + l*16 within the window's 2 KB.
    //   dst: flat v*1024 + l*16, +4096, +8192, +12288
    //        -> pieces 0..3 = A blocks +0..3, pieces 4..7 = B blocks +0..3,
    //           piece p at p*2048 with lo/hi 1 KB halves.
    const size_t soff = (size_t)(wave & 1) * 1024 + (size_t)lane * 16;
    const unsigned char* srcA0 = neb + (size_t)(i0 / 32 + (wave >> 1)) * 16384 + soff;
    const unsigned char* srcB0 = neb + (size_t)(j0 / 32 + (wave >> 1)) * 16384 + soff;
    unsigned char* dA0 = smem[0] + (u32)wave * 1024 + (u32)lane * 16;

    floatx16 acc[2][2];
    #pragma unroll
    for (int a = 0; a < 2; ++a)
        #pragma unroll
        for (int b = 0; b < 2; ++b)
            #pragma unroll
            for (int e = 0; e < 16; ++e) acc[a][b][e] = 0.0f;

    intx4 stA0, stA1, stB0, stB1;              // in-flight staging registers

    // prologue: stage window 0 into buf 0
    {
        stA0 = *(const intx4*)(srcA0);
        stA1 = *(const intx4*)(srcA0 + 32768);
        stB0 = *(const intx4*)(srcB0);
        stB1 = *(const intx4*)(srcB0 + 32768);
        *(intx4*)(dA0)          = stA0;
        *(intx4*)(dA0 + 4096)   = stA1;
        *(intx4*)(dA0 + 8192)   = stB0;
        *(intx4*)(dA0 + 12288)  = stB1;
    }
    __syncthreads();                           // window 0 published

    #pragma unroll
    for (int w = 0; w < 8; ++w) {
        if (w < 7) {                           // issue next window's loads EARLY
            const size_t ko = (size_t)(w + 1) * 2048;
            stA0 = *(const intx4*)(srcA0 + ko);
            stA1 = *(const intx4*)(srcA0 + 32768 + ko);
            stB0 = *(const intx4*)(srcB0 + ko);
            stB1 = *(const intx4*)(srcB0 + 32768 + ko);
        }
        const unsigned char* bp = smem[w & 1];
        // A frags: pieces wrow*2 + t; B frags: pieces 4 + wcol*2 + t.
        // lo 16B at piece*2048 + lane*16, hi at +1024 (verified order).
        intx8 fa[2], fb[2];
        #pragma unroll
        for (int t = 0; t < 2; ++t) {
            intx4 alo = *(const intx4*)(bp + (size_t)(wrow * 2 + t) * 2048 + lane * 16);
            intx4 ahi = *(const intx4*)(bp + (size_t)(wrow * 2 + t) * 2048 + 1024 + lane * 16);
            fa[t] = __builtin_shufflevector(alo, ahi, 0, 1, 2, 3, 4, 5, 6, 7);
            intx4 blo = *(const intx4*)(bp + 8192 + (size_t)(wcol * 2 + t) * 2048 + lane * 16);
            intx4 bhi = *(const intx4*)(bp + 8192 + (size_t)(wcol * 2 + t) * 2048 + 1024 + lane * 16);
            fb[t] = __builtin_shufflevector(blo, bhi, 0, 1, 2, 3, 4, 5, 6, 7);
        }
        #pragma unroll
        for (int ti = 0; ti < 2; ++ti)
            #pragma unroll
            for (int tj = 0; tj < 2; ++tj)
                acc[ti][tj] = __builtin_amdgcn_mfma_scale_f32_32x32x64_f8f6f4(
                    fa[ti], fb[tj], acc[ti][tj],
                    0, 0,                // cbsz=FP8(e4m3), blgp=FP8(e4m3)
                    0, 0x7f7f7f7f,       // scale_a opsel, E8M0 = 127 -> 1.0
                    0, 0x7f7f7f7f);      // scale_b
        if (w < 7) {                           // write-late: vmcnt wait rode under MFMAs
            unsigned char* dn = smem[(w + 1) & 1] + (u32)wave * 1024 + (u32)lane * 16;
            *(intx4*)(dn)          = stA0;     // buf^1's reads ended before the
            *(intx4*)(dn + 4096)   = stA1;     // PREVIOUS barrier -> safe to overwrite
            *(intx4*)(dn + 8192)   = stB0;
            *(intx4*)(dn + 12288)  = stB1;
            __syncthreads();                   // publish window w+1
        }
    }

    // 32x32 C/D layout: col = lane&31, row = (r&3) + 8*(r>>2) + 4*(lane>>5)
    const int hi  = lane >> 5, l31 = lane & 31;

    // row-sums: exp(2*c) summed over this block's 128 cols -> slot bj*2+wcol
    const int prow = bj * 2 + wcol;
    const int R0   = i0 + wrow * 64;
    #pragma unroll
    for (int ti = 0; ti < 2; ++ti) {
        #pragma unroll
        for (int r = 0; r < 16; ++r) {
            float ss = __expf(2.0f * acc[ti][0][r]) + __expf(2.0f * acc[ti][1][r]);
            #pragma unroll
            for (int off = 1; off < 32; off <<= 1) ss += __shfl_xor(ss, off);
            if (l31 == 0) {
                int rowg = R0 + ti * 32 + (r & 3) + 8 * (r >> 2) + 4 * hi;
                partial[(size_t)prow * N + rowg] = ss;
            }
        }
    }
    // col-sums (symmetry: = row-sums of skipped tile (bj,bi)) -> slot bi*2+wrow
    if (bi < bj) {
        const int pcol = bi * 2 + wrow;
        const int C0   = j0 + wcol * 64;
        #pragma unroll
        for (int tj = 0; tj < 2; ++tj) {
            float css = 0.f;
            #pragma unroll
            for (int ti = 0; ti < 2; ++ti)
                #pragma unroll
                for (int r = 0; r < 16; ++r) css += __expf(2.0f * acc[ti][tj][r]);
            css += __shfl_xor(css, 32);
            if (hi == 0) partial[(size_t)pcol * N + (C0 + tj * 32 + l31)] = css;
        }
    }
}

__global__ __launch_bounds__(256) void k_final(const float* __restrict__ partial,
                                               const float* __restrict__ pos,
                                               float* __restrict__ out) {
    int tid = threadIdx.x;
    int row = blockIdx.x * 64 + (tid >> 2);
    int sub = tid & 3;
    float S = 0.f;
    #pragma unroll
    for (int i = 0; i < 32; ++i) S += partial[(size_t)(sub + i * 4) * N + row];
    S += __shfl_xor(S, 1);
    S += __shfl_xor(S, 2);
    float val = (sub == 0) ? (logf(S) - 2.0f * pos[row]) : 0.0f;
    #pragma unroll
    for (int off = 4; off < 64; off <<= 1) val += __shfl_xor(val, off);
    if ((tid & 63) == 0) atomicAdd(out, val * (1.0f / (2.0f * N)));
}

extern "C" void kernel_launch(void* const* d_in, const int* in_sizes, int n_in,
                              void* d_out, int out_size, void* d_ws, size_t ws_size,
                              hipStream_t stream) {
    const float* emb = (const float*)d_in[0];
    const float* tgt = (const float*)d_in[1];
    unsigned char* neb = (unsigned char*)d_ws;                                   // 4 MB fp8 ne (MX layout)
    float* pos     = (float*)((char*)d_ws + (size_t)N * D);                      // 32 KB
    float* partial = (float*)((char*)d_ws + (size_t)N * D + (size_t)N * 4);      // 4 MB
    float* out = (float*)d_out;

    k_norm<<<N / 4, 256, 0, stream>>>(emb, tgt, neb, pos, out);
    k_gemm<<<NT * (NT + 1) / 2, 256, 0, stream>>>(neb, partial);
    k_final<<<N / 64, 256, 0, stream>>>(partial, pos, out);
}

// Round 8
// 133.388 us; speedup vs baseline: 1.2863x; 1.2863x over previous
//
#include <hip/hip_runtime.h>

// ContrastiveLoss: loss = sum_n [ log(sum_j exp(2*<ne_n,ne_j>)) - 2*<ne_n,nt_n> ] / (2N)
// N=8192, D=512.
// R19 = R18 with ONE variable changed: __launch_bounds__(256,3) -> (256,2).
// R18 post-mortem: three structurally different LDS stagings (R13 DMA, R17
// DMA-piecewise, R18 reg-staged) produced byte-identical pathology (VGPR 84,
// FETCH 123 MB, WRITE 210 MB, Mfma 7%, ~93 us) -- the co-varying factor is
// the launch-bounds cap, and reported VGPR == cap/2 every time:
//   (256,4) cap 128 -> VGPR 64, WRITE 336 MB, 145 us
//   (256,3) cap 168 -> VGPR 84, WRITE ~210 MB, ~93 us  [x4 replications]
//   (256,2) cap 256 -> VGPR 128, WRITE 4.7 MB, 58.7 us [R16, clean]
// Inference: with MFMA acc in the unified file the allocator splits the
// budget ~50/50 arch/acc; at (256,3) the arch half (84) < live set -> scratch
// spill at HBM latency. R13/R17/R18 tested spill, not LDS dedup. This round
// runs the SAME dedup structure spill-free at (256,2): arch budget 128 >=
// live ~85.
//   k_gemm : reg-staged LDS dedup (global->VGPR->ds_write_b128->ds_read),
//            2x16 KB double buffer, one barrier per 64-k window; loads for
//            w+1 issue before MFMA(w), ds_write after (write-late). L2
//            demand 266 MB (half of R16's 532 MB duplicated direct loads).
//            Compute: 2x2 waves x 2x2 mfma_scale_f32_32x32x64_f8f6f4, unit
//            E8M0 scales; 32x32 C/D epilogue (col=lane&31,
//            row=(r&3)+8*(r>>2)+4*(lane>>5)); symmetric triangle; XCD sched.
//   k_norm : unchanged (R13/R14/R17/R18-verified MX 16B-half layout).
//   k_final: unchanged.

typedef __attribute__((ext_vector_type(16))) float floatx16;
typedef __attribute__((ext_vector_type(4)))  int   intx4;
typedef __attribute__((ext_vector_type(8)))  int   intx8;
typedef unsigned int u32;

#define N 8192
#define D 512
#define NT 64            // 128-row tiles per dim

// Per-XCD segment tables: 5 segments each = [diag36, off64, off64, off64, half32].
__device__ __constant__ unsigned char seg_ga[8][5] = {
    {0,0,0,0,0},{1,1,1,1,0},{2,2,2,2,2},{3,3,3,3,2},
    {4,0,0,0,4},{5,1,1,1,4},{6,2,3,4,6},{7,4,5,5,6}};
__device__ __constant__ unsigned char seg_gb[8][5] = {
    {0,2,3,4,1},{1,2,3,4,1},{2,5,6,7,3},{3,5,6,7,3},
    {4,5,6,7,5},{5,5,6,7,5},{6,4,4,6,7},{7,7,6,7,7}};

__global__ __launch_bounds__(256) void k_norm(const float* __restrict__ emb,
                                              const float* __restrict__ tgt,
                                              unsigned char* __restrict__ neb,
                                              float* __restrict__ pos,
                                              float* __restrict__ out) {
    if (blockIdx.x == 0 && threadIdx.x == 0) *out = 0.0f;   // replaces memset dispatch
    int wave = threadIdx.x >> 6;
    int lane = threadIdx.x & 63;
    int row  = blockIdx.x * 4 + wave;          // one wave per row; lane holds k=lane*8..+8
    const float4* e4 = (const float4*)(emb + (size_t)row * D) + lane * 2;
    const float4* t4 = (const float4*)(tgt + (size_t)row * D) + lane * 2;
    float4 e0 = e4[0], e1 = e4[1];
    float4 t0 = t4[0], t1 = t4[1];
    float ee = e0.x*e0.x + e0.y*e0.y + e0.z*e0.z + e0.w*e0.w
             + e1.x*e1.x + e1.y*e1.y + e1.z*e1.z + e1.w*e1.w;
    float tt = t0.x*t0.x + t0.y*t0.y + t0.z*t0.z + t0.w*t0.w
             + t1.x*t1.x + t1.y*t1.y + t1.z*t1.z + t1.w*t1.w;
    float et = e0.x*t0.x + e0.y*t0.y + e0.z*t0.z + e0.w*t0.w
             + e1.x*t1.x + e1.y*t1.y + e1.z*t1.z + e1.w*t1.w;
    #pragma unroll
    for (int off = 1; off < 64; off <<= 1) {
        ee += __shfl_xor(ee, off);
        tt += __shfl_xor(tt, off);
        et += __shfl_xor(et, off);
    }
    float se = fmaxf(sqrtf(ee), 1e-12f);
    float st = fmaxf(sqrtf(tt), 1e-12f);
    if (lane == 0) pos[row] = et / (se * st);
    float inv = 1.0f / se;
    // pack 8 e4m3 bytes (k ascending) via HW RNE converts
    int w0 = __builtin_amdgcn_cvt_pk_fp8_f32(e0.x * inv, e0.y * inv, 0, false);
    w0     = __builtin_amdgcn_cvt_pk_fp8_f32(e0.z * inv, e0.w * inv, w0, true);
    int w1 = __builtin_amdgcn_cvt_pk_fp8_f32(e1.x * inv, e1.y * inv, 0, false);
    w1     = __builtin_amdgcn_cvt_pk_fp8_f32(e1.z * inv, e1.w * inv, w1, true);
    uint2 pk; pk.x = (unsigned)w0; pk.y = (unsigned)w1;
    // MX layout (verified R13/R14/R17/R18). Row r, byte kb = lane*8:
    //   block b32 = r>>5 (16 KB), window w = kb>>6 (2 KB), khalf g = (kb>>5)&1,
    //   16B-half h = (kb>>4)&1, uint2 parity = lane&1.
    //   byte addr = b32*16384 + w*2048 + h*1024 + (g*32 + (r&31))*16 + (lane&1)*8
    size_t u2idx = (size_t)(row >> 5) * 2048
                 + (size_t)(lane >> 3) * 256
                 + (size_t)((lane >> 1) & 1) * 128
                 + (size_t)(((lane >> 2) & 1) * 32 + (row & 31)) * 2
                 + (lane & 1);
    ((uint2*)neb)[u2idx] = pk;
}

__global__ __launch_bounds__(256, 2) void k_gemm(const unsigned char* __restrict__ neb,
                                                 float* __restrict__ partial) {
    // XCD-partitioned decode: x = XCD stream, s = sequence within stream
    const int x = (int)(blockIdx.x & 7);
    int s = (int)(blockIdx.x >> 3);          // 0..259
    int seg, u;
    if (s < 36)       { seg = 0; u = s; }
    else if (s < 100) { seg = 1; u = s - 36; }
    else if (s < 164) { seg = 2; u = s - 100; }
    else if (s < 228) { seg = 3; u = s - 164; }
    else              { seg = 4; u = s - 228 + ((x & 1) ? 32 : 0); }
    const int ga = seg_ga[x][seg], gb = seg_gb[x][seg];
    int bi, bj;
    if (seg == 0) {                           // diag supertile: tri decode in 8x8
        int di = 0;
        while (u >= 8 - di) { u -= 8 - di; ++di; }
        bi = ga * 8 + di; bj = gb * 8 + di + u;
    } else {
        bi = ga * 8 + (u >> 3); bj = gb * 8 + (u & 7);
    }

    __shared__ unsigned char smem[2][16384];   // double-buffered 64-k window: A 8K | B 8K

    const int tid  = threadIdx.x;
    const int i0   = bi * 128, j0 = bj * 128;
    const int wave = tid >> 6, lane = tid & 63;
    const int wrow = wave >> 1, wcol = wave & 1;   // 2x2 waves, each 64x64

    // --- staging plan (R17/R18 addressing, ds_write instead of DMA):
    // wave v, lane l handles 4 x 16 B per window:
    //   src: A blocks (i0/32 + (v>>1)) and +2; B blocks (j0/32 + (v>>1)) and +2,
    //        each at (v&1)*1024 + l*16 within the window's 2 KB.
    //   dst: flat v*1024 + l*16, +4096, +8192, +12288
    //        -> pieces 0..3 = A blocks +0..3, pieces 4..7 = B blocks +0..3,
    //           piece p at p*2048 with lo/hi 1 KB halves.
    const size_t soff = (size_t)(wave & 1) * 1024 + (size_t)lane * 16;
    const unsigned char* srcA0 = neb + (size_t)(i0 / 32 + (wave >> 1)) * 16384 + soff;
    const unsigned char* srcB0 = neb + (size_t)(j0 / 32 + (wave >> 1)) * 16384 + soff;
    unsigned char* dA0 = smem[0] + (u32)wave * 1024 + (u32)lane * 16;

    floatx16 acc[2][2];
    #pragma unroll
    for (int a = 0; a < 2; ++a)
        #pragma unroll
        for (int b = 0; b < 2; ++b)
            #pragma unroll
            for (int e = 0; e < 16; ++e) acc[a][b][e] = 0.0f;

    intx4 stA0, stA1, stB0, stB1;              // in-flight staging registers

    // prologue: stage window 0 into buf 0
    {
        stA0 = *(const intx4*)(srcA0);
        stA1 = *(const intx4*)(srcA0 + 32768);
        stB0 = *(const intx4*)(srcB0);
        stB1 = *(const intx4*)(srcB0 + 32768);
        *(intx4*)(dA0)          = stA0;
        *(intx4*)(dA0 + 4096)   = stA1;
        *(intx4*)(dA0 + 8192)   = stB0;
        *(intx4*)(dA0 + 12288)  = stB1;
    }
    __syncthreads();                           // window 0 published

    #pragma unroll
    for (int w = 0; w < 8; ++w) {
        if (w < 7) {                           // issue next window's loads EARLY
            const size_t ko = (size_t)(w + 1) * 2048;
            stA0 = *(const intx4*)(srcA0 + ko);
            stA1 = *(const intx4*)(srcA0 + 32768 + ko);
            stB0 = *(const intx4*)(srcB0 + ko);
            stB1 = *(const intx4*)(srcB0 + 32768 + ko);
        }
        const unsigned char* bp = smem[w & 1];
        // A frags: pieces wrow*2 + t; B frags: pieces 4 + wcol*2 + t.
        // lo 16B at piece*2048 + lane*16, hi at +1024 (verified order).
        intx8 fa[2], fb[2];
        #pragma unroll
        for (int t = 0; t < 2; ++t) {
            intx4 alo = *(const intx4*)(bp + (size_t)(wrow * 2 + t) * 2048 + lane * 16);
            intx4 ahi = *(const intx4*)(bp + (size_t)(wrow * 2 + t) * 2048 + 1024 + lane * 16);
            fa[t] = __builtin_shufflevector(alo, ahi, 0, 1, 2, 3, 4, 5, 6, 7);
            intx4 blo = *(const intx4*)(bp + 8192 + (size_t)(wcol * 2 + t) * 2048 + lane * 16);
            intx4 bhi = *(const intx4*)(bp + 8192 + (size_t)(wcol * 2 + t) * 2048 + 1024 + lane * 16);
            fb[t] = __builtin_shufflevector(blo, bhi, 0, 1, 2, 3, 4, 5, 6, 7);
        }
        #pragma unroll
        for (int ti = 0; ti < 2; ++ti)
            #pragma unroll
            for (int tj = 0; tj < 2; ++tj)
                acc[ti][tj] = __builtin_amdgcn_mfma_scale_f32_32x32x64_f8f6f4(
                    fa[ti], fb[tj], acc[ti][tj],
                    0, 0,                // cbsz=FP8(e4m3), blgp=FP8(e4m3)
                    0, 0x7f7f7f7f,       // scale_a opsel, E8M0 = 127 -> 1.0
                    0, 0x7f7f7f7f);      // scale_b
        if (w < 7) {                           // write-late: vmcnt wait rode under MFMAs
            unsigned char* dn = smem[(w + 1) & 1] + (u32)wave * 1024 + (u32)lane * 16;
            *(intx4*)(dn)          = stA0;     // buf^1's reads ended before the
            *(intx4*)(dn + 4096)   = stA1;     // PREVIOUS barrier -> safe to overwrite
            *(intx4*)(dn + 8192)   = stB0;
            *(intx4*)(dn + 12288)  = stB1;
            __syncthreads();                   // publish window w+1
        }
    }

    // 32x32 C/D layout: col = lane&31, row = (r&3) + 8*(r>>2) + 4*(lane>>5)
    const int hi  = lane >> 5, l31 = lane & 31;

    // row-sums: exp(2*c) summed over this block's 128 cols -> slot bj*2+wcol
    const int prow = bj * 2 + wcol;
    const int R0   = i0 + wrow * 64;
    #pragma unroll
    for (int ti = 0; ti < 2; ++ti) {
        #pragma unroll
        for (int r = 0; r < 16; ++r) {
            float ss = __expf(2.0f * acc[ti][0][r]) + __expf(2.0f * acc[ti][1][r]);
            #pragma unroll
            for (int off = 1; off < 32; off <<= 1) ss += __shfl_xor(ss, off);
            if (l31 == 0) {
                int rowg = R0 + ti * 32 + (r & 3) + 8 * (r >> 2) + 4 * hi;
                partial[(size_t)prow * N + rowg] = ss;
            }
        }
    }
    // col-sums (symmetry: = row-sums of skipped tile (bj,bi)) -> slot bi*2+wrow
    if (bi < bj) {
        const int pcol = bi * 2 + wrow;
        const int C0   = j0 + wcol * 64;
        #pragma unroll
        for (int tj = 0; tj < 2; ++tj) {
            float css = 0.f;
            #pragma unroll
            for (int ti = 0; ti < 2; ++ti)
                #pragma unroll
                for (int r = 0; r < 16; ++r) css += __expf(2.0f * acc[ti][tj][r]);
            css += __shfl_xor(css, 32);
            if (hi == 0) partial[(size_t)pcol * N + (C0 + tj * 32 + l31)] = css;
        }
    }
}

__global__ __launch_bounds__(256) void k_final(const float* __restrict__ partial,
                                               const float* __restrict__ pos,
                                               float* __restrict__ out) {
    int tid = threadIdx.x;
    int row = blockIdx.x * 64 + (tid >> 2);
    int sub = tid & 3;
    float S = 0.f;
    #pragma unroll
    for (int i = 0; i < 32; ++i) S += partial[(size_t)(sub + i * 4) * N + row];
    S += __shfl_xor(S, 1);
    S += __shfl_xor(S, 2);
    float val = (sub == 0) ? (logf(S) - 2.0f * pos[row]) : 0.0f;
    #pragma unroll
    for (int off = 4; off < 64; off <<= 1) val += __shfl_xor(val, off);
    if ((tid & 63) == 0) atomicAdd(out, val * (1.0f / (2.0f * N)));
}

extern "C" void kernel_launch(void* const* d_in, const int* in_sizes, int n_in,
                              void* d_out, int out_size, void* d_ws, size_t ws_size,
                              hipStream_t stream) {
    const float* emb = (const float*)d_in[0];
    const float* tgt = (const float*)d_in[1];
    unsigned char* neb = (unsigned char*)d_ws;                                   // 4 MB fp8 ne (MX layout)
    float* pos     = (float*)((char*)d_ws + (size_t)N * D);                      // 32 KB
    float* partial = (float*)((char*)d_ws + (size_t)N * D + (size_t)N * 4);      // 4 MB
    float* out = (float*)d_out;

    k_norm<<<N / 4, 256, 0, stream>>>(emb, tgt, neb, pos, out);
    k_gemm<<<NT * (NT + 1) / 2, 256, 0, stream>>>(neb, partial);
    k_final<<<N / 64, 256, 0, stream>>>(partial, pos, out);
}

// Round 9
// 118.327 us; speedup vs baseline: 1.4500x; 1.1273x over previous
//
#include <hip/hip_runtime.h>

// ContrastiveLoss: loss = sum_n [ log(sum_j exp(2*<ne_n,ne_j>)) - 2*<ne_n,nt_n> ] / (2N)
// N=8192, D=512.
// R20: buy occupancy with a smaller accumulator. R19 post-mortem: spill fixed
// (WRITE 336->4.7 MB at (256,2); reported VGPR = allocated/2 i.e. PAIRS), but
// gemm stuck at 55.5 us ~= R16's 58.7 despite halved L2 demand -- realized BW
// 4.8-9.1 TB/s << L2's ~35 -> LATENCY/OCCUPANCY-bound. Cross-round scaling:
// R12 @16 waves/CU -> 13.3 TB/s; R16/R19 @8 waves/CU -> 9.1/4.8. Throughput
// tracks waves in flight; the acc-64 (64x64) MX tile forces live ~176 regs ->
// (256,2) -> 8 waves/CU. Fix: wave tile 32x64 -> acc 2xfloatx16 = 32 regs,
// live ~90 -> fits 128-reg budget -> __launch_bounds__(512,4): 8-wave blocks,
// 2 blocks/CU, 16 waves/CU.
//   k_gemm : 128x128 block tile (verified XCD/triangle schedule), 8 waves =
//            4 row-groups(32) x 2 col-groups(64). LDS dedup (266 MB L2
//            demand): wave v verbatim-copies piece v (2 KB) per 64-k window,
//            reg-staged (global->VGPR->ds_write_b128), double-buffered,
//            write-late, one barrier per window. Compute: 2x
//            mfma_scale_f32_32x32x64_f8f6f4 (unit E8M0) per wave per window.
//            Row-sums as before (slot bj*2+wcol); col-sums now span 4
//            row-waves -> LDS cross-wave reduce post-loop, writers waves 0/1
//            -> slot bi*2+wcol (same uniqueness argument, k_final unchanged).
//   k_norm : unchanged (R13-R19-verified MX 16B-half-interleaved layout).
//   k_final: unchanged.

typedef __attribute__((ext_vector_type(16))) float floatx16;
typedef __attribute__((ext_vector_type(4)))  int   intx4;
typedef __attribute__((ext_vector_type(8)))  int   intx8;
typedef unsigned int u32;

#define N 8192
#define D 512
#define NT 64            // 128-row tiles per dim

// Per-XCD segment tables: 5 segments each = [diag36, off64, off64, off64, half32].
__device__ __constant__ unsigned char seg_ga[8][5] = {
    {0,0,0,0,0},{1,1,1,1,0},{2,2,2,2,2},{3,3,3,3,2},
    {4,0,0,0,4},{5,1,1,1,4},{6,2,3,4,6},{7,4,5,5,6}};
__device__ __constant__ unsigned char seg_gb[8][5] = {
    {0,2,3,4,1},{1,2,3,4,1},{2,5,6,7,3},{3,5,6,7,3},
    {4,5,6,7,5},{5,5,6,7,5},{6,4,4,6,7},{7,7,6,7,7}};

__global__ __launch_bounds__(256) void k_norm(const float* __restrict__ emb,
                                              const float* __restrict__ tgt,
                                              unsigned char* __restrict__ neb,
                                              float* __restrict__ pos,
                                              float* __restrict__ out) {
    if (blockIdx.x == 0 && threadIdx.x == 0) *out = 0.0f;   // replaces memset dispatch
    int wave = threadIdx.x >> 6;
    int lane = threadIdx.x & 63;
    int row  = blockIdx.x * 4 + wave;          // one wave per row; lane holds k=lane*8..+8
    const float4* e4 = (const float4*)(emb + (size_t)row * D) + lane * 2;
    const float4* t4 = (const float4*)(tgt + (size_t)row * D) + lane * 2;
    float4 e0 = e4[0], e1 = e4[1];
    float4 t0 = t4[0], t1 = t4[1];
    float ee = e0.x*e0.x + e0.y*e0.y + e0.z*e0.z + e0.w*e0.w
             + e1.x*e1.x + e1.y*e1.y + e1.z*e1.z + e1.w*e1.w;
    float tt = t0.x*t0.x + t0.y*t0.y + t0.z*t0.z + t0.w*t0.w
             + t1.x*t1.x + t1.y*t1.y + t1.z*t1.z + t1.w*t1.w;
    float et = e0.x*t0.x + e0.y*t0.y + e0.z*t0.z + e0.w*t0.w
             + e1.x*t1.x + e1.y*t1.y + e1.z*t1.z + e1.w*t1.w;
    #pragma unroll
    for (int off = 1; off < 64; off <<= 1) {
        ee += __shfl_xor(ee, off);
        tt += __shfl_xor(tt, off);
        et += __shfl_xor(et, off);
    }
    float se = fmaxf(sqrtf(ee), 1e-12f);
    float st = fmaxf(sqrtf(tt), 1e-12f);
    if (lane == 0) pos[row] = et / (se * st);
    float inv = 1.0f / se;
    // pack 8 e4m3 bytes (k ascending) via HW RNE converts
    int w0 = __builtin_amdgcn_cvt_pk_fp8_f32(e0.x * inv, e0.y * inv, 0, false);
    w0     = __builtin_amdgcn_cvt_pk_fp8_f32(e0.z * inv, e0.w * inv, w0, true);
    int w1 = __builtin_amdgcn_cvt_pk_fp8_f32(e1.x * inv, e1.y * inv, 0, false);
    w1     = __builtin_amdgcn_cvt_pk_fp8_f32(e1.z * inv, e1.w * inv, w1, true);
    uint2 pk; pk.x = (unsigned)w0; pk.y = (unsigned)w1;
    // MX layout (verified R13-R19). Row r, byte kb = lane*8:
    //   block b32 = r>>5 (16 KB), window w = kb>>6 (2 KB), khalf g = (kb>>5)&1,
    //   16B-half h = (kb>>4)&1, uint2 parity = lane&1.
    //   byte addr = b32*16384 + w*2048 + h*1024 + (g*32 + (r&31))*16 + (lane&1)*8
    size_t u2idx = (size_t)(row >> 5) * 2048
                 + (size_t)(lane >> 3) * 256
                 + (size_t)((lane >> 1) & 1) * 128
                 + (size_t)(((lane >> 2) & 1) * 32 + (row & 31)) * 2
                 + (lane & 1);
    ((uint2*)neb)[u2idx] = pk;
}

__global__ __launch_bounds__(512, 4) void k_gemm(const unsigned char* __restrict__ neb,
                                                 float* __restrict__ partial) {
    // XCD-partitioned decode: x = XCD stream, s = sequence within stream
    const int x = (int)(blockIdx.x & 7);
    int s = (int)(blockIdx.x >> 3);          // 0..259
    int seg, u;
    if (s < 36)       { seg = 0; u = s; }
    else if (s < 100) { seg = 1; u = s - 36; }
    else if (s < 164) { seg = 2; u = s - 100; }
    else if (s < 228) { seg = 3; u = s - 164; }
    else              { seg = 4; u = s - 228 + ((x & 1) ? 32 : 0); }
    const int ga = seg_ga[x][seg], gb = seg_gb[x][seg];
    int bi, bj;
    if (seg == 0) {                           // diag supertile: tri decode in 8x8
        int di = 0;
        while (u >= 8 - di) { u -= 8 - di; ++di; }
        bi = ga * 8 + di; bj = gb * 8 + di + u;
    } else {
        bi = ga * 8 + (u >> 3); bj = gb * 8 + (u & 7);
    }

    __shared__ unsigned char smem[2][16384];   // double-buffered 64-k window: A 8K | B 8K

    const int tid  = threadIdx.x;
    const int i0   = bi * 128, j0 = bj * 128;
    const int wave = tid >> 6, lane = tid & 63;
    const int wrow = wave >> 1, wcol = wave & 1;   // 4 row-groups x 2 col-groups
    const int hi   = lane >> 5, l31 = lane & 31;

    // staging: wave v verbatim-copies piece v (2 KB): pieces 0..3 = A blocks
    // i0/32+0..3, pieces 4..7 = B blocks j0/32+0..3. Lane copies 32 B.
    const int sblk = (wave < 4) ? (i0 / 32 + wave) : (j0 / 32 + (wave - 4));
    const unsigned char* srcP = neb + (size_t)sblk * 16384 + (size_t)lane * 32;
    const u32 dstoff = (u32)wave * 2048 + (u32)lane * 32;

    floatx16 acc[2];
    #pragma unroll
    for (int b = 0; b < 2; ++b)
        #pragma unroll
        for (int e = 0; e < 16; ++e) acc[b][e] = 0.0f;

    intx4 st0, st1;                            // in-flight staging registers

    // prologue: stage window 0 into buf 0
    st0 = *(const intx4*)(srcP);
    st1 = *(const intx4*)(srcP + 16);
    *(intx4*)(smem[0] + dstoff)      = st0;
    *(intx4*)(smem[0] + dstoff + 16) = st1;
    __syncthreads();                           // window 0 published

    #pragma unroll
    for (int w = 0; w < 8; ++w) {
        if (w < 7) {                           // issue next window's loads EARLY
            const size_t ko = (size_t)(w + 1) * 2048;
            st0 = *(const intx4*)(srcP + ko);
            st1 = *(const intx4*)(srcP + ko + 16);
        }
        const unsigned char* bp = smem[w & 1];
        // A frag: piece wrow; B frags: pieces 4 + wcol*2 + tj.
        // lo 16B at piece*2048 + lane*16, hi at +1024 (verified order).
        intx4 alo = *(const intx4*)(bp + (size_t)wrow * 2048 + lane * 16);
        intx4 ahi = *(const intx4*)(bp + (size_t)wrow * 2048 + 1024 + lane * 16);
        intx8 fa  = __builtin_shufflevector(alo, ahi, 0, 1, 2, 3, 4, 5, 6, 7);
        intx8 fb[2];
        #pragma unroll
        for (int tj = 0; tj < 2; ++tj) {
            intx4 blo = *(const intx4*)(bp + 8192 + (size_t)(wcol * 2 + tj) * 2048 + lane * 16);
            intx4 bhi = *(const intx4*)(bp + 8192 + (size_t)(wcol * 2 + tj) * 2048 + 1024 + lane * 16);
            fb[tj] = __builtin_shufflevector(blo, bhi, 0, 1, 2, 3, 4, 5, 6, 7);
        }
        #pragma unroll
        for (int tj = 0; tj < 2; ++tj)
            acc[tj] = __builtin_amdgcn_mfma_scale_f32_32x32x64_f8f6f4(
                fa, fb[tj], acc[tj],
                0, 0,                // cbsz=FP8(e4m3), blgp=FP8(e4m3)
                0, 0x7f7f7f7f,       // scale_a opsel, E8M0 = 127 -> 1.0
                0, 0x7f7f7f7f);      // scale_b
        if (w < 7) {                           // write-late: vmcnt wait rides under MFMAs
            unsigned char* dn = smem[(w + 1) & 1] + dstoff;
            *(intx4*)(dn)      = st0;          // buf^1's reads ended before the
            *(intx4*)(dn + 16) = st1;          // PREVIOUS barrier -> safe to overwrite
            __syncthreads();                   // publish window w+1
        }
    }

    // 32x32 C/D layout: col = lane&31, row = (r&3) + 8*(r>>2) + 4*(lane>>5)
    // row-sums: exp(2*c) summed over this block's 128 cols; the two col-halves
    // (wcol) write separate slots -> slot bj*2 + wcol, rows i0 + wrow*32 + ...
    const int prow = bj * 2 + wcol;
    const int R0   = i0 + wrow * 32;
    #pragma unroll
    for (int r = 0; r < 16; ++r) {
        float ss = __expf(2.0f * acc[0][r]) + __expf(2.0f * acc[1][r]);
        #pragma unroll
        for (int off = 1; off < 32; off <<= 1) ss += __shfl_xor(ss, off);
        if (l31 == 0) {
            int rowg = R0 + (r & 3) + 8 * (r >> 2) + 4 * hi;
            partial[(size_t)prow * N + rowg] = ss;
        }
    }
    // col-sums (symmetry: = row-sums of skipped tile (bj,bi)): 4 row-waves
    // contribute per col -> LDS cross-wave reduce, writers waves 0/1 ->
    // slot bi*2 + wcol (unique vs row slots since (bj,bi) not in triangle).
    if (bi < bj) {
        __syncthreads();                       // K-loop reads done; reuse LDS
        float* smf = (float*)smem;             // [4][128] col partials
        #pragma unroll
        for (int tj = 0; tj < 2; ++tj) {
            float css = 0.f;
            #pragma unroll
            for (int r = 0; r < 16; ++r) css += __expf(2.0f * acc[tj][r]);
            css += __shfl_xor(css, 32);        // combine the two 16-row halves
            if (hi == 0) smf[wrow * 128 + wcol * 64 + tj * 32 + l31] = css;
        }
        __syncthreads();
        if (wave < 2) {                        // wave 0: cols 0..63; wave 1: 64..127
            int c = wave * 64 + lane;
            float sum = smf[c] + smf[128 + c] + smf[256 + c] + smf[384 + c];
            partial[(size_t)(bi * 2 + wave) * N + (j0 + c)] = sum;
        }
    }
}

__global__ __launch_bounds__(256) void k_final(const float* __restrict__ partial,
                                               const float* __restrict__ pos,
                                               float* __restrict__ out) {
    int tid = threadIdx.x;
    int row = blockIdx.x * 64 + (tid >> 2);
    int sub = tid & 3;
    float S = 0.f;
    #pragma unroll
    for (int i = 0; i < 32; ++i) S += partial[(size_t)(sub + i * 4) * N + row];
    S += __shfl_xor(S, 1);
    S += __shfl_xor(S, 2);
    float val = (sub == 0) ? (logf(S) - 2.0f * pos[row]) : 0.0f;
    #pragma unroll
    for (int off = 4; off < 64; off <<= 1) val += __shfl_xor(val, off);
    if ((tid & 63) == 0) atomicAdd(out, val * (1.0f / (2.0f * N)));
}

extern "C" void kernel_launch(void* const* d_in, const int* in_sizes, int n_in,
                              void* d_out, int out_size, void* d_ws, size_t ws_size,
                              hipStream_t stream) {
    const float* emb = (const float*)d_in[0];
    const float* tgt = (const float*)d_in[1];
    unsigned char* neb = (unsigned char*)d_ws;                                   // 4 MB fp8 ne (MX layout)
    float* pos     = (float*)((char*)d_ws + (size_t)N * D);                      // 32 KB
    float* partial = (float*)((char*)d_ws + (size_t)N * D + (size_t)N * 4);      // 4 MB
    float* out = (float*)d_out;

    k_norm<<<N / 4, 256, 0, stream>>>(emb, tgt, neb, pos, out);
    k_gemm<<<NT * (NT + 1) / 2, 512, 0, stream>>>(neb, partial);
    k_final<<<N / 64, 256, 0, stream>>>(partial, pos, out);
}